// Round 1
// baseline (12482.517 us; speedup 1.0000x reference)
//
#include <hip/hip_runtime.h>
#include <stdint.h>

typedef unsigned short u16;
typedef unsigned int u32;
typedef __attribute__((ext_vector_type(4))) float f32x4;
typedef __attribute__((ext_vector_type(8))) short bf16x8;

constexpr int kT = 8192;   // sequence length
constexpr int kD = 512;    // word emb dim
constexpr int kH = 2048;   // hidden
constexpr int kH3 = 6144;  // 3*H
constexpr int kS = 512;    // segments
constexpr int kSeg = 16;   // tokens per segment
constexpr int kNWG2 = 256; // persistent WGs for upper GRU

__device__ __forceinline__ float bf2f(u16 u) {
  union { float f; u32 u; } v; v.u = ((u32)u) << 16; return v.f;
}
__device__ __forceinline__ u16 f2bf(float f) {
  union { float f; u32 u; } v; v.f = f;
  u32 lsb = (v.u >> 16) & 1u;
  v.u += 0x7fffu + lsb;          // round-to-nearest-even
  return (u16)(v.u >> 16);
}
__device__ __forceinline__ float sigm(float x) { return 1.f / (1.f + expf(-x)); }

// async global->LDS, 16B per lane; LDS dest = wave-uniform base + lane*16
__device__ __forceinline__ void g2l16(const u16* g, u16* l) {
  __builtin_amdgcn_global_load_lds(
      (const __attribute__((address_space(1))) u32*)g,
      (__attribute__((address_space(3))) u32*)l, 16, 0, 0);
}

// ---------------- f32 -> bf16 convert ----------------
__global__ void cvt_bf16(const float* __restrict__ in, u16* __restrict__ out, int n4) {
  int i = blockIdx.x * blockDim.x + threadIdx.x;
  if (i >= n4) return;
  const float4 v = *(const float4*)(in + (size_t)i * 4);
  uint2 o;
  o.x = (u32)f2bf(v.x) | ((u32)f2bf(v.y) << 16);
  o.y = (u32)f2bf(v.z) | ((u32)f2bf(v.w) << 16);
  *(uint2*)(out + (size_t)i * 4) = o;
}

// ---------------- bf16 GEMM  C(MxN) = A(MxK,lda) * B(NxK,ldb)^T ----------------
// EPI 0: C_f32 = acc      EPI 2: Obf = bf16(tanh(acc + bias[col]))
// M%128==0, N%128==0, K%64==0 assumed.
template<int EPI>
__global__ __launch_bounds__(256)
void gemm_bt(const u16* __restrict__ A, int lda,
             const u16* __restrict__ B, int ldb,
             float* __restrict__ C,
             u16* __restrict__ Obf, const float* __restrict__ bias,
             int M, int N, int K)
{
  __shared__ u16 lsA[128 * 64];
  __shared__ u16 lsB[128 * 64];
  const int tid = threadIdx.x;
  const int w = tid >> 6, lane = tid & 63;
  const int wr = w >> 1, wc = w & 1;
  const int arow0 = blockIdx.y * 128;
  const int brow0 = blockIdx.x * 128;
  const int srow = w * 32 + (lane >> 3);
  const int scol = (lane & 7) * 8;
  const u16* gA = A + (size_t)(arow0 + srow) * lda + scol;
  const u16* gB = B + (size_t)(brow0 + srow) * ldb + scol;
  u16* lAbase = &lsA[(w * 32) * 64];
  u16* lBbase = &lsB[(w * 32) * 64];

  f32x4 acc[4][4];
#pragma unroll
  for (int m = 0; m < 4; ++m)
#pragma unroll
    for (int n = 0; n < 4; ++n) acc[m][n] = (f32x4)0.f;

  const int fr = lane & 15;
  const int kq = lane >> 4;

  for (int kt = 0; kt < K; kt += 64) {
#pragma unroll
    for (int i = 0; i < 4; ++i) {
      g2l16(gA + (size_t)i * 8 * lda + kt, lAbase + i * 8 * 64);
      g2l16(gB + (size_t)i * 8 * ldb + kt, lBbase + i * 8 * 64);
    }
    __syncthreads();
#pragma unroll
    for (int kk = 0; kk < 2; ++kk) {
      bf16x8 af[4], bq[4];
#pragma unroll
      for (int m = 0; m < 4; ++m)
        af[m] = *(const bf16x8*)&lsA[(wr * 64 + m * 16 + fr) * 64 + kk * 32 + kq * 8];
#pragma unroll
      for (int n = 0; n < 4; ++n)
        bq[n] = *(const bf16x8*)&lsB[(wc * 64 + n * 16 + fr) * 64 + kk * 32 + kq * 8];
#pragma unroll
      for (int m = 0; m < 4; ++m)
#pragma unroll
        for (int n = 0; n < 4; ++n)
          acc[m][n] = __builtin_amdgcn_mfma_f32_16x16x32_bf16(af[m], bq[n], acc[m][n], 0, 0, 0);
    }
    __syncthreads();
  }

#pragma unroll
  for (int m = 0; m < 4; ++m) {
#pragma unroll
    for (int n = 0; n < 4; ++n) {
      const int row0 = arow0 + wr * 64 + m * 16 + kq * 4;
      const int col = brow0 + wc * 64 + n * 16 + fr;
      if (EPI == 0) {
#pragma unroll
        for (int i = 0; i < 4; ++i)
          C[(size_t)(row0 + i) * N + col] = acc[m][n][i];
      } else {
        const float bv = bias[col];
#pragma unroll
        for (int i = 0; i < 4; ++i)
          Obf[(size_t)(row0 + i) * N + col] = f2bf(tanhf(acc[m][n][i] + bv));
      }
    }
  }
}

// ---------------- lower-GRU gates (one local step, all 512 segments) ----------------
__global__ __launch_bounds__(256) void gru1_gates(
    const float* __restrict__ gi, const float* __restrict__ gh,
    const float* __restrict__ bi, const float* __restrict__ bh,
    u16* __restrict__ h_bf, u16* __restrict__ outs_bf, int t)
{
  const int idx = blockIdx.x * 256 + threadIdx.x;  // 512*2048 exact
  const int seg = idx >> 11, j = idx & 2047;
  const int base = seg * kH3;
  const float r = sigm(gi[base + j] + bi[j] + gh[base + j] + bh[j]);
  const float z = sigm(gi[base + kH + j] + bi[kH + j] + gh[base + kH + j] + bh[kH + j]);
  const float gin = gi[base + 2 * kH + j] + bi[2 * kH + j];
  const float ghn = gh[base + 2 * kH + j] + bh[2 * kH + j];
  const float n = tanhf(gin + r * ghn);
  const float hprev = bf2f(h_bf[seg * kH + j]);
  const float hn = (1.f - z) * n + z * hprev;
  const u16 hb = f2bf(hn);
  h_bf[seg * kH + j] = hb;
  outs_bf[(size_t)(seg * kSeg + t) * kH + j] = hb;
}

// ---------------- degenerate softmax weight + per-segment column max ----------------
__global__ __launch_bounds__(256) void seg_weight_max(
    const u16* __restrict__ embh, const float* __restrict__ wa,
    u16* __restrict__ seg_bf)
{
  __shared__ float wrow[16];
  const int s = blockIdx.x, tid = threadIdx.x;
  const int w = tid >> 6, lane = tid & 63;
#pragma unroll
  for (int rr = 0; rr < 4; ++rr) {
    const int r = w * 4 + rr;
    const u16* row = embh + ((size_t)s * kSeg + r) * kH;
    float p = 0.f;
#pragma unroll
    for (int k = 0; k < 32; ++k) {
      const int c = lane + 64 * k;
      p += bf2f(row[c]) * wa[c];
    }
#pragma unroll
    for (int off = 32; off; off >>= 1) p += __shfl_down(p, off, 64);
    if (lane == 0) { const float e = expf(p); wrow[r] = e / (e + 1e-4f); }
  }
  __syncthreads();
#pragma unroll
  for (int i = 0; i < 8; ++i) {
    const int c = tid + 256 * i;
    float m = -1e30f;
#pragma unroll
    for (int r = 0; r < 16; ++r)
      m = fmaxf(m, wrow[r] * bf2f(embh[((size_t)s * kSeg + r) * kH + c]));
    seg_bf[(size_t)s * kH + c] = f2bf(m);
  }
}

// ---------------- upper GRU: persistent, 512 steps, grid barrier per step ----------------
__global__ __launch_bounds__(256)
void gru2_persistent(const u16* __restrict__ Wh2bf, const float* __restrict__ gi2,
                     const float* __restrict__ bi2, const float* __restrict__ bh2,
                     float* __restrict__ h2buf,   // 2*2048 f32, double-buffered
                     u16* __restrict__ outs2,     // 512*2048 bf16
                     int* __restrict__ bar)       // [0]=counter [1]=generation
{
  __shared__ u16 wl[24 * kH];      // 96 KiB: rows {j, H+j, 2H+j} for 8 owned j's
  __shared__ float hl[kH];         // 8 KiB
  __shared__ float rowsum[24];
  __shared__ float gil[24];
  const int wg = blockIdx.x, tid = threadIdx.x;
  const int g0 = wg * 8;
#pragma unroll
  for (int lr = 0; lr < 24; ++lr) {
    const int grow = (lr >> 3) * kH + g0 + (lr & 7);
    *(uint4*)&wl[lr * kH + tid * 8] = *(const uint4*)&Wh2bf[(size_t)grow * kH + tid * 8];
  }
  const int w = tid >> 6, lane = tid & 63;
  for (int t = 0; t < 512; ++t) {
    const int cur = t & 1;
    const float* hsrc = h2buf + cur * kH;
#pragma unroll
    for (int i = 0; i < 8; ++i) {
      const int c = tid + 256 * i;
      hl[c] = __hip_atomic_load(&hsrc[c], __ATOMIC_RELAXED, __HIP_MEMORY_SCOPE_AGENT);
    }
    if (tid < 24) {
      const int gate = tid >> 3, j = tid & 7;
      gil[tid] = gi2[(size_t)t * kH3 + gate * kH + g0 + j];
    }
    __syncthreads();
#pragma unroll
    for (int rr = 0; rr < 6; ++rr) {
      const int lr = w * 6 + rr;
      float p = 0.f;
#pragma unroll
      for (int k = 0; k < 16; ++k) {
        const int c = 2 * lane + 128 * k;
        const u32 wp = *(const u32*)&wl[lr * kH + c];
        const float2 hv = *(const float2*)&hl[c];
        p += bf2f((u16)(wp & 0xffffu)) * hv.x + bf2f((u16)(wp >> 16)) * hv.y;
      }
#pragma unroll
      for (int off = 32; off; off >>= 1) p += __shfl_down(p, off, 64);
      if (lane == 0) rowsum[lr] = p;
    }
    __syncthreads();
    if (tid < 8) {
      const int jj = g0 + tid;
      const float r = sigm(gil[tid] + bi2[jj] + rowsum[tid] + bh2[jj]);
      const float z = sigm(gil[8 + tid] + bi2[kH + jj] + rowsum[8 + tid] + bh2[kH + jj]);
      const float n = tanhf(gil[16 + tid] + bi2[2 * kH + jj] +
                            r * (rowsum[16 + tid] + bh2[2 * kH + jj]));
      const float hn = (1.f - z) * n + z * hl[jj];
      __hip_atomic_store(&h2buf[(1 - cur) * kH + jj], hn,
                         __ATOMIC_RELEASE, __HIP_MEMORY_SCOPE_AGENT);
      outs2[(size_t)t * kH + jj] = f2bf(hn);
    }
    __syncthreads();
    if (tid == 0) {
      const int prev = __hip_atomic_fetch_add(&bar[0], 1, __ATOMIC_ACQ_REL,
                                              __HIP_MEMORY_SCOPE_AGENT);
      if (prev == kNWG2 - 1) {
        __hip_atomic_store(&bar[0], 0, __ATOMIC_RELAXED, __HIP_MEMORY_SCOPE_AGENT);
        __hip_atomic_store(&bar[1], t + 1, __ATOMIC_RELEASE, __HIP_MEMORY_SCOPE_AGENT);
      } else {
        while (__hip_atomic_load(&bar[1], __ATOMIC_ACQUIRE,
                                 __HIP_MEMORY_SCOPE_AGENT) < t + 1) {
          __builtin_amdgcn_s_sleep(8);
        }
      }
    }
    __syncthreads();
  }
}

// ---------------- w2 then final column max ----------------
__global__ void calc_w2(const u16* __restrict__ e2, const float* __restrict__ wa2,
                        float* __restrict__ w2) {
  const int s = blockIdx.x, lane = threadIdx.x;  // 64 threads
  float p = 0.f;
#pragma unroll
  for (int k = 0; k < 32; ++k) {
    const int c = lane + 64 * k;
    p += bf2f(e2[(size_t)s * kH + c]) * wa2[c];
  }
#pragma unroll
  for (int off = 32; off; off >>= 1) p += __shfl_down(p, off, 64);
  if (lane == 0) { const float e = expf(p); w2[s] = e / (e + 1e-4f); }
}

__global__ void final_max(const u16* __restrict__ e2, const float* __restrict__ w2,
                          float* __restrict__ out) {
  const int j = blockIdx.x * blockDim.x + threadIdx.x;  // 2048
  float m = -1e30f;
  for (int s = 0; s < 512; ++s)
    m = fmaxf(m, w2[s] * bf2f(e2[(size_t)s * kH + j]));
  out[j] = m;
}

// ---------------- host ----------------
extern "C" void kernel_launch(void* const* d_in, const int* in_sizes, int n_in,
                              void* d_out, int out_size, void* d_ws, size_t ws_size,
                              hipStream_t stream)
{
  (void)in_sizes; (void)n_in; (void)out_size; (void)ws_size;
  const float* sent = (const float*)d_in[0];
  const float* Wi1f = (const float*)d_in[1];
  const float* Wh1f = (const float*)d_in[2];
  const float* bi1  = (const float*)d_in[3];
  const float* bh1  = (const float*)d_in[4];
  const float* Wi2f = (const float*)d_in[5];
  const float* Wh2f = (const float*)d_in[6];
  const float* bi2  = (const float*)d_in[7];
  const float* bh2  = (const float*)d_in[8];
  const float* Wlf  = (const float*)d_in[9];
  const float* bl   = (const float*)d_in[10];
  const float* wa   = (const float*)d_in[11];
  const float* Wl2f = (const float*)d_in[12];
  const float* bl2  = (const float*)d_in[13];
  const float* wa2  = (const float*)d_in[14];
  float* out = (float*)d_out;

  char* base = (char*)d_ws;
  size_t off = 0;
  auto alloc = [&](size_t b) { char* p = base + off; off += (b + 255) & ~(size_t)255; return p; };
  u16* sent_bf = (u16*)alloc((size_t)kT * kD * 2);   // freed after phase B -> embh alias
  u16* Wi1b    = (u16*)alloc((size_t)kH3 * kD * 2);
  u16* Wh1b    = (u16*)alloc((size_t)kH3 * kH * 2);
  u16* Wi2b    = (u16*)alloc((size_t)kH3 * kH * 2);
  u16* Wh2b    = (u16*)alloc((size_t)kH3 * kH * 2);
  u16* Wlb     = (u16*)alloc((size_t)kH * kH * 2);
  u16* Wl2b    = (u16*)alloc((size_t)kH * kH * 2);
  float* gi_buf = (float*)alloc((size_t)kS * kH3 * 4);
  float* gh_buf = (float*)alloc((size_t)kS * kH3 * 4);
  u16* h1b     = (u16*)alloc((size_t)kS * kH * 2);
  u16* outs_bf = (u16*)alloc((size_t)kT * kH * 2);
  u16* seg_bf  = (u16*)alloc((size_t)kS * kH * 2);
  float* h2buf = (float*)alloc(2 * kH * 4);
  u16* outs2   = (u16*)alloc((size_t)kS * kH * 2);
  u16* e2b     = (u16*)alloc((size_t)kS * kH * 2);
  float* w2    = (float*)alloc(kS * 4);
  int* bar     = (int*)alloc(256);
  // aliases over dead regions
  u16* embh  = sent_bf;   // 33.5 MB fits in sent_bf+Wi1b+Wh1b (39.8 MB)
  float* gi2 = gi_buf;

  hipMemsetAsync(h1b, 0, (size_t)kS * kH * 2, stream);
  hipMemsetAsync(h2buf, 0, 2 * kH * 4, stream);
  hipMemsetAsync(bar, 0, 256, stream);

  auto cvt = [&](const float* src, u16* dst, int n) {
    const int n4 = n / 4;
    cvt_bf16<<<dim3((n4 + 255) / 256), dim3(256), 0, stream>>>(src, dst, n4);
  };
  cvt(sent, sent_bf, kT * kD);
  cvt(Wi1f, Wi1b, kH3 * kD);
  cvt(Wh1f, Wh1b, kH3 * kH);
  cvt(Wi2f, Wi2b, kH3 * kH);
  cvt(Wh2f, Wh2b, kH3 * kH);
  cvt(Wlf, Wlb, kH * kH);
  cvt(Wl2f, Wl2b, kH * kH);

  // ---- phase B: lower GRU, 16 batched steps over 512 independent chains ----
  for (int t = 0; t < kSeg; ++t) {
    gemm_bt<0><<<dim3(kH3 / 128, kS / 128), dim3(256), 0, stream>>>(
        h1b, kH, Wh1b, kH, gh_buf, nullptr, nullptr, kS, kH3, kH);
    gemm_bt<0><<<dim3(kH3 / 128, kS / 128), dim3(256), 0, stream>>>(
        sent_bf + t * kD, kSeg * kD, Wi1b, kD, gi_buf, nullptr, nullptr, kS, kH3, kD);
    gru1_gates<<<dim3(kS * kH / 256), dim3(256), 0, stream>>>(
        gi_buf, gh_buf, bi1, bh1, h1b, outs_bf, t);
  }
  // ---- phase C: emb_h = tanh(outs @ Wl^T + bl) ----
  gemm_bt<2><<<dim3(kH / 128, kT / 128), dim3(256), 0, stream>>>(
      outs_bf, kH, Wlb, kH, nullptr, embh, bl, kT, kH, kH);
  // ---- phase D: w, weighted, segment max ----
  seg_weight_max<<<dim3(kS), dim3(256), 0, stream>>>(embh, wa, seg_bf);
  // ---- phase E: gi2 = seg @ Wi2^T ----
  gemm_bt<0><<<dim3(kH3 / 128, kS / 128), dim3(256), 0, stream>>>(
      seg_bf, kH, Wi2b, kH, gi2, nullptr, nullptr, kS, kH3, kH);
  // ---- phase F: upper GRU, 512 sequential steps, persistent kernel ----
  gru2_persistent<<<dim3(kNWG2), dim3(256), 0, stream>>>(
      Wh2b, gi2, bi2, bh2, h2buf, outs2, bar);
  // ---- phase G: e2 = tanh(outs2 @ Wl2^T + bl2), w2, final max ----
  gemm_bt<2><<<dim3(kH / 128, kS / 128), dim3(256), 0, stream>>>(
      outs2, kH, Wl2b, kH, nullptr, e2b, bl2, kS, kH, kH);
  calc_w2<<<dim3(kS), dim3(64), 0, stream>>>(e2b, wa2, w2);
  final_max<<<dim3(kH / 256), dim3(256), 0, stream>>>(e2b, w2, out);
}

// Round 2
// 4265.434 us; speedup vs baseline: 2.9264x; 2.9264x over previous
//
#include <hip/hip_runtime.h>
#include <stdint.h>

typedef unsigned short u16;
typedef unsigned int u32;
typedef unsigned long long u64;
typedef __attribute__((ext_vector_type(4))) float f32x4;
typedef __attribute__((ext_vector_type(8))) short bf16x8;

constexpr int kT = 8192;   // sequence length
constexpr int kD = 512;    // word emb dim
constexpr int kH = 2048;   // hidden
constexpr int kH3 = 6144;  // 3*H
constexpr int kS = 512;    // segments
constexpr int kSeg = 16;   // tokens per segment
constexpr int kNWG2 = 256; // persistent WGs for upper GRU
constexpr int kREP = 8;    // h-broadcast replicas

__device__ __forceinline__ float bf2f(u16 u) {
  union { float f; u32 u; } v; v.u = ((u32)u) << 16; return v.f;
}
__device__ __forceinline__ u16 f2bf(float f) {
  union { float f; u32 u; } v; v.f = f;
  u32 lsb = (v.u >> 16) & 1u;
  v.u += 0x7fffu + lsb;          // round-to-nearest-even
  return (u16)(v.u >> 16);
}
__device__ __forceinline__ float sigm(float x) { return 1.f / (1.f + expf(-x)); }

// async global->LDS, 16B per lane; LDS dest = wave-uniform base + lane*16
__device__ __forceinline__ void g2l16(const u16* g, u16* l) {
  __builtin_amdgcn_global_load_lds(
      (const __attribute__((address_space(1))) u32*)g,
      (__attribute__((address_space(3))) u32*)l, 16, 0, 0);
}

__device__ __forceinline__ u64 aload64(const u64* p) {
  return __hip_atomic_load(p, __ATOMIC_RELAXED, __HIP_MEMORY_SCOPE_AGENT);
}
__device__ __forceinline__ void astore64(u64* p, u64 v) {
  __hip_atomic_store(p, v, __ATOMIC_RELAXED, __HIP_MEMORY_SCOPE_AGENT);
}

// ---------------- f32 -> bf16 convert ----------------
__global__ void cvt_bf16(const float* __restrict__ in, u16* __restrict__ out, int n4) {
  int i = blockIdx.x * blockDim.x + threadIdx.x;
  if (i >= n4) return;
  const float4 v = *(const float4*)(in + (size_t)i * 4);
  uint2 o;
  o.x = (u32)f2bf(v.x) | ((u32)f2bf(v.y) << 16);
  o.y = (u32)f2bf(v.z) | ((u32)f2bf(v.w) << 16);
  *(uint2*)(out + (size_t)i * 4) = o;
}

// ---------------- bf16 GEMM  C(MxN) = A(MxK,lda) * B(NxK,ldb)^T ----------------
template<int EPI>
__global__ __launch_bounds__(256)
void gemm_bt(const u16* __restrict__ A, int lda,
             const u16* __restrict__ B, int ldb,
             float* __restrict__ C,
             u16* __restrict__ Obf, const float* __restrict__ bias,
             int M, int N, int K)
{
  __shared__ u16 lsA[128 * 64];
  __shared__ u16 lsB[128 * 64];
  const int tid = threadIdx.x;
  const int w = tid >> 6, lane = tid & 63;
  const int wr = w >> 1, wc = w & 1;
  const int arow0 = blockIdx.y * 128;
  const int brow0 = blockIdx.x * 128;
  const int srow = w * 32 + (lane >> 3);
  const int scol = (lane & 7) * 8;
  const u16* gA = A + (size_t)(arow0 + srow) * lda + scol;
  const u16* gB = B + (size_t)(brow0 + srow) * ldb + scol;
  u16* lAbase = &lsA[(w * 32) * 64];
  u16* lBbase = &lsB[(w * 32) * 64];

  f32x4 acc[4][4];
#pragma unroll
  for (int m = 0; m < 4; ++m)
#pragma unroll
    for (int n = 0; n < 4; ++n) acc[m][n] = (f32x4)0.f;

  const int fr = lane & 15;
  const int kq = lane >> 4;

  for (int kt = 0; kt < K; kt += 64) {
#pragma unroll
    for (int i = 0; i < 4; ++i) {
      g2l16(gA + (size_t)i * 8 * lda + kt, lAbase + i * 8 * 64);
      g2l16(gB + (size_t)i * 8 * ldb + kt, lBbase + i * 8 * 64);
    }
    __syncthreads();
#pragma unroll
    for (int kk = 0; kk < 2; ++kk) {
      bf16x8 af[4], bq[4];
#pragma unroll
      for (int m = 0; m < 4; ++m)
        af[m] = *(const bf16x8*)&lsA[(wr * 64 + m * 16 + fr) * 64 + kk * 32 + kq * 8];
#pragma unroll
      for (int n = 0; n < 4; ++n)
        bq[n] = *(const bf16x8*)&lsB[(wc * 64 + n * 16 + fr) * 64 + kk * 32 + kq * 8];
#pragma unroll
      for (int m = 0; m < 4; ++m)
#pragma unroll
        for (int n = 0; n < 4; ++n)
          acc[m][n] = __builtin_amdgcn_mfma_f32_16x16x32_bf16(af[m], bq[n], acc[m][n], 0, 0, 0);
    }
    __syncthreads();
  }

#pragma unroll
  for (int m = 0; m < 4; ++m) {
#pragma unroll
    for (int n = 0; n < 4; ++n) {
      const int row0 = arow0 + wr * 64 + m * 16 + kq * 4;
      const int col = brow0 + wc * 64 + n * 16 + fr;
      if (EPI == 0) {
#pragma unroll
        for (int i = 0; i < 4; ++i)
          C[(size_t)(row0 + i) * N + col] = acc[m][n][i];
      } else {
        const float bv = bias[col];
#pragma unroll
        for (int i = 0; i < 4; ++i)
          Obf[(size_t)(row0 + i) * N + col] = f2bf(tanhf(acc[m][n][i] + bv));
      }
    }
  }
}

// ---------------- lower-GRU gates (one local step, all 512 segments) ----------------
__global__ __launch_bounds__(256) void gru1_gates(
    const float* __restrict__ gi, const float* __restrict__ gh,
    const float* __restrict__ bi, const float* __restrict__ bh,
    u16* __restrict__ h_bf, u16* __restrict__ outs_bf, int t)
{
  const int idx = blockIdx.x * 256 + threadIdx.x;  // 512*2048 exact
  const int seg = idx >> 11, j = idx & 2047;
  const int base = seg * kH3;
  const float r = sigm(gi[base + j] + bi[j] + gh[base + j] + bh[j]);
  const float z = sigm(gi[base + kH + j] + bi[kH + j] + gh[base + kH + j] + bh[kH + j]);
  const float gin = gi[base + 2 * kH + j] + bi[2 * kH + j];
  const float ghn = gh[base + 2 * kH + j] + bh[2 * kH + j];
  const float n = tanhf(gin + r * ghn);
  const float hprev = bf2f(h_bf[seg * kH + j]);
  const float hn = (1.f - z) * n + z * hprev;
  const u16 hb = f2bf(hn);
  h_bf[seg * kH + j] = hb;
  outs_bf[(size_t)(seg * kSeg + t) * kH + j] = hb;
}

// ---------------- degenerate softmax weight + per-segment column max ----------------
__global__ __launch_bounds__(256) void seg_weight_max(
    const u16* __restrict__ embh, const float* __restrict__ wa,
    u16* __restrict__ seg_bf)
{
  __shared__ float wrow[16];
  const int s = blockIdx.x, tid = threadIdx.x;
  const int w = tid >> 6, lane = tid & 63;
#pragma unroll
  for (int rr = 0; rr < 4; ++rr) {
    const int r = w * 4 + rr;
    const u16* row = embh + ((size_t)s * kSeg + r) * kH;
    float p = 0.f;
#pragma unroll
    for (int k = 0; k < 32; ++k) {
      const int c = lane + 64 * k;
      p += bf2f(row[c]) * wa[c];
    }
#pragma unroll
    for (int off = 32; off; off >>= 1) p += __shfl_down(p, off, 64);
    if (lane == 0) { const float e = expf(p); wrow[r] = e / (e + 1e-4f); }
  }
  __syncthreads();
#pragma unroll
  for (int i = 0; i < 8; ++i) {
    const int c = tid + 256 * i;
    float m = -1e30f;
#pragma unroll
    for (int r = 0; r < 16; ++r)
      m = fmaxf(m, wrow[r] * bf2f(embh[((size_t)s * kSeg + r) * kH + c]));
    seg_bf[(size_t)s * kH + c] = f2bf(m);
  }
}

// ---------------- upper GRU: persistent, 512 steps ----------------
// All cross-WG traffic via RELAXED agent-scope atomics (sc1, coherence-point
// direct) -> no acquire/release cache maintenance on the critical path.
// h broadcast: bf16-packed u64, kREP replicas. Barrier: monotonic two-level
// (8 group counters -> root -> 8 generation lines), 128B-separated.
__global__ __launch_bounds__(256)
void gru2_persistent(const u16* __restrict__ Wh2bf, const float* __restrict__ gi2,
                     const float* __restrict__ bi2, const float* __restrict__ bh2,
                     u64* __restrict__ hrep,      // [2][kREP][512] u64 (bf16 x4)
                     u16* __restrict__ outs2,     // 512*2048 bf16
                     int* __restrict__ barz)      // arr[g*32], root[256], gen[512+g*32]
{
  __shared__ u16 wl[24 * kH];                 // 96 KiB
  __shared__ alignas(16) u16 hlb[kH];         // 4 KiB bf16 h
  __shared__ float gil_all[512 * 24];         // 48 KiB: gi2 slice for this WG
  __shared__ float rowsum[24];
  __shared__ alignas(16) u16 hnl[8];
  const int wg = blockIdx.x, tid = threadIdx.x;
  const int g0 = wg * 8;
  const int grp = wg & 7;
#pragma unroll
  for (int lr = 0; lr < 24; ++lr) {
    const int grow = (lr >> 3) * kH + g0 + (lr & 7);
    *(uint4*)&wl[lr * kH + tid * 8] = *(const uint4*)&Wh2bf[(size_t)grow * kH + tid * 8];
  }
  for (int i = tid; i < 512 * 24; i += 256) {
    const int t = i / 24, idx = i - t * 24;
    gil_all[i] = gi2[(size_t)t * kH3 + (idx >> 3) * kH + g0 + (idx & 7)];
  }
  float bir = 0, biz = 0, bin = 0, bhr = 0, bhz = 0, bhn = 0;
  if (tid < 8) {
    const int jj = g0 + tid;
    bir = bi2[jj]; biz = bi2[kH + jj]; bin = bi2[2 * kH + jj];
    bhr = bh2[jj]; bhz = bh2[kH + jj]; bhn = bh2[2 * kH + jj];
  }
  const int w = tid >> 6, lane = tid & 63;

  for (int t = 0; t < 512; ++t) {
    const int cur = t & 1;
    // ---- broadcast-in: 2 x u64 atomic loads per thread from own replica ----
    const u64* hs = hrep + ((size_t)cur * kREP + grp) * 512;
    const u64 v0 = aload64(&hs[2 * tid]);
    const u64 v1 = aload64(&hs[2 * tid + 1]);
    ((u64*)hlb)[2 * tid] = v0;
    ((u64*)hlb)[2 * tid + 1] = v1;
    __syncthreads();
    // ---- matvec: 6 rows per wave, bf16*bf16 -> f32 ----
#pragma unroll
    for (int rr = 0; rr < 6; ++rr) {
      const int lr = w * 6 + rr;
      const u32* wr2 = (const u32*)&wl[lr * kH];
      const u32* hr2 = (const u32*)hlb;
      float p = 0.f;
#pragma unroll
      for (int k = 0; k < 16; ++k) {
        const int c = lane + 64 * k;
        const u32 wp = wr2[c], hp = hr2[c];
        p += bf2f((u16)(wp & 0xffffu)) * bf2f((u16)(hp & 0xffffu));
        p += bf2f((u16)(wp >> 16)) * bf2f((u16)(hp >> 16));
      }
#pragma unroll
      for (int off = 32; off; off >>= 1) p += __shfl_down(p, off, 64);
      if (lane == 0) rowsum[lr] = p;
    }
    __syncthreads();
    // ---- gates ----
    if (tid < 8) {
      const float r = sigm(gil_all[t * 24 + tid] + bir + rowsum[tid] + bhr);
      const float z = sigm(gil_all[t * 24 + 8 + tid] + biz + rowsum[8 + tid] + bhz);
      const float n = tanhf(gil_all[t * 24 + 16 + tid] + bin +
                            r * (rowsum[16 + tid] + bhn));
      const float hn = (1.f - z) * n + z * bf2f(hlb[g0 + tid]);
      hnl[tid] = f2bf(hn);
    }
    __syncthreads();
    // ---- broadcast-out: 8 bf16 to kREP replicas + outs2 ----
    if (tid < 2 * kREP) {
      const int rep = tid >> 1, k = tid & 1;
      const u64 val = ((const u64*)hnl)[k];
      astore64(&hrep[((size_t)(1 - cur) * kREP + rep) * 512 + wg * 2 + k], val);
    }
    if (tid == 0)
      *(uint4*)&outs2[(size_t)t * kH + g0] = *(const uint4*)hnl;
    __syncthreads();   // drains the stores (vmcnt) before arrival
    // ---- two-level monotonic barrier ----
    if (tid == 0) {
      const int prev = __hip_atomic_fetch_add(&barz[grp * 32], 1,
                                              __ATOMIC_RELAXED, __HIP_MEMORY_SCOPE_AGENT);
      bool release = false;
      if (prev == 32 * t + 31) {
        const int rp = __hip_atomic_fetch_add(&barz[256], 1,
                                              __ATOMIC_RELAXED, __HIP_MEMORY_SCOPE_AGENT);
        if (rp == 8 * t + 7) {
          release = true;
#pragma unroll
          for (int r = 0; r < 8; ++r)
            __hip_atomic_store(&barz[512 + r * 32], t + 1,
                               __ATOMIC_RELAXED, __HIP_MEMORY_SCOPE_AGENT);
        }
      }
      if (!release) {
        while (__hip_atomic_load(&barz[512 + grp * 32],
                                 __ATOMIC_RELAXED, __HIP_MEMORY_SCOPE_AGENT) < t + 1)
          __builtin_amdgcn_s_sleep(1);
      }
    }
    __syncthreads();
  }
}

// ---------------- w2 then final column max ----------------
__global__ void calc_w2(const u16* __restrict__ e2, const float* __restrict__ wa2,
                        float* __restrict__ w2) {
  const int s = blockIdx.x, lane = threadIdx.x;  // 64 threads
  float p = 0.f;
#pragma unroll
  for (int k = 0; k < 32; ++k) {
    const int c = lane + 64 * k;
    p += bf2f(e2[(size_t)s * kH + c]) * wa2[c];
  }
#pragma unroll
  for (int off = 32; off; off >>= 1) p += __shfl_down(p, off, 64);
  if (lane == 0) { const float e = expf(p); w2[s] = e / (e + 1e-4f); }
}

__global__ void final_max(const u16* __restrict__ e2, const float* __restrict__ w2,
                          float* __restrict__ out) {
  const int j = blockIdx.x * blockDim.x + threadIdx.x;  // 2048
  float m = -1e30f;
  for (int s = 0; s < 512; ++s)
    m = fmaxf(m, w2[s] * bf2f(e2[(size_t)s * kH + j]));
  out[j] = m;
}

// ---------------- host ----------------
extern "C" void kernel_launch(void* const* d_in, const int* in_sizes, int n_in,
                              void* d_out, int out_size, void* d_ws, size_t ws_size,
                              hipStream_t stream)
{
  (void)in_sizes; (void)n_in; (void)out_size; (void)ws_size;
  const float* sent = (const float*)d_in[0];
  const float* Wi1f = (const float*)d_in[1];
  const float* Wh1f = (const float*)d_in[2];
  const float* bi1  = (const float*)d_in[3];
  const float* bh1  = (const float*)d_in[4];
  const float* Wi2f = (const float*)d_in[5];
  const float* Wh2f = (const float*)d_in[6];
  const float* bi2  = (const float*)d_in[7];
  const float* bh2  = (const float*)d_in[8];
  const float* Wlf  = (const float*)d_in[9];
  const float* bl   = (const float*)d_in[10];
  const float* wa   = (const float*)d_in[11];
  const float* Wl2f = (const float*)d_in[12];
  const float* bl2  = (const float*)d_in[13];
  const float* wa2  = (const float*)d_in[14];
  float* out = (float*)d_out;

  char* base = (char*)d_ws;
  size_t off = 0;
  auto alloc = [&](size_t b) { char* p = base + off; off += (b + 255) & ~(size_t)255; return p; };
  u16* sent_bf = (u16*)alloc((size_t)kT * kD * 2);   // freed after phase B -> embh alias
  u16* Wi1b    = (u16*)alloc((size_t)kH3 * kD * 2);
  u16* Wh1b    = (u16*)alloc((size_t)kH3 * kH * 2);
  u16* Wi2b    = (u16*)alloc((size_t)kH3 * kH * 2);
  u16* Wh2b    = (u16*)alloc((size_t)kH3 * kH * 2);
  u16* Wlb     = (u16*)alloc((size_t)kH * kH * 2);
  u16* Wl2b    = (u16*)alloc((size_t)kH * kH * 2);
  float* gi_buf = (float*)alloc((size_t)kS * kH3 * 4);
  float* gh_buf = (float*)alloc((size_t)kS * kH3 * 4);
  u16* h1b     = (u16*)alloc((size_t)kS * kH * 2);
  u16* outs_bf = (u16*)alloc((size_t)kT * kH * 2);
  u16* seg_bf  = (u16*)alloc((size_t)kS * kH * 2);
  u64* hrep    = (u64*)alloc((size_t)2 * kREP * 512 * 8);
  u16* outs2   = (u16*)alloc((size_t)kS * kH * 2);
  u16* e2b     = (u16*)alloc((size_t)kS * kH * 2);
  float* w2    = (float*)alloc(kS * 4);
  int* barz    = (int*)alloc(4096);
  // aliases over dead regions
  u16* embh  = sent_bf;   // 33.5 MB fits in sent_bf+Wi1b+Wh1b (39.8 MB)
  float* gi2 = gi_buf;

  hipMemsetAsync(h1b, 0, (size_t)kS * kH * 2, stream);
  hipMemsetAsync(hrep, 0, (size_t)2 * kREP * 512 * 8, stream);
  hipMemsetAsync(barz, 0, 4096, stream);

  auto cvt = [&](const float* src, u16* dst, int n) {
    const int n4 = n / 4;
    cvt_bf16<<<dim3((n4 + 255) / 256), dim3(256), 0, stream>>>(src, dst, n4);
  };
  cvt(sent, sent_bf, kT * kD);
  cvt(Wi1f, Wi1b, kH3 * kD);
  cvt(Wh1f, Wh1b, kH3 * kH);
  cvt(Wi2f, Wi2b, kH3 * kH);
  cvt(Wh2f, Wh2b, kH3 * kH);
  cvt(Wlf, Wlb, kH * kH);
  cvt(Wl2f, Wl2b, kH * kH);

  // ---- phase B: lower GRU, 16 batched steps over 512 independent chains ----
  for (int t = 0; t < kSeg; ++t) {
    gemm_bt<0><<<dim3(kH3 / 128, kS / 128), dim3(256), 0, stream>>>(
        h1b, kH, Wh1b, kH, gh_buf, nullptr, nullptr, kS, kH3, kH);
    gemm_bt<0><<<dim3(kH3 / 128, kS / 128), dim3(256), 0, stream>>>(
        sent_bf + t * kD, kSeg * kD, Wi1b, kD, gi_buf, nullptr, nullptr, kS, kH3, kD);
    gru1_gates<<<dim3(kS * kH / 256), dim3(256), 0, stream>>>(
        gi_buf, gh_buf, bi1, bh1, h1b, outs_bf, t);
  }
  // ---- phase C: emb_h = tanh(outs @ Wl^T + bl) ----
  gemm_bt<2><<<dim3(kH / 128, kT / 128), dim3(256), 0, stream>>>(
      outs_bf, kH, Wlb, kH, nullptr, embh, bl, kT, kH, kH);
  // ---- phase D: w, weighted, segment max ----
  seg_weight_max<<<dim3(kS), dim3(256), 0, stream>>>(embh, wa, seg_bf);
  // ---- phase E: gi2 = seg @ Wi2^T ----
  gemm_bt<0><<<dim3(kH3 / 128, kS / 128), dim3(256), 0, stream>>>(
      seg_bf, kH, Wi2b, kH, gi2, nullptr, nullptr, kS, kH3, kH);
  // ---- phase F: upper GRU, 512 sequential steps, persistent kernel ----
  gru2_persistent<<<dim3(kNWG2), dim3(256), 0, stream>>>(
      Wh2b, gi2, bi2, bh2, hrep, outs2, barz);
  // ---- phase G: e2 = tanh(outs2 @ Wl2^T + bl2), w2, final max ----
  gemm_bt<2><<<dim3(kH / 128, kS / 128), dim3(256), 0, stream>>>(
      outs2, kH, Wl2b, kH, nullptr, e2b, bl2, kS, kH, kH);
  calc_w2<<<dim3(kS), dim3(64), 0, stream>>>(e2b, wa2, w2);
  final_max<<<dim3(kH / 256), dim3(256), 0, stream>>>(e2b, w2, out);
}

// Round 3
// 2958.253 us; speedup vs baseline: 4.2196x; 1.4419x over previous
//
#include <hip/hip_runtime.h>
#include <stdint.h>

typedef unsigned short u16;
typedef unsigned int u32;
typedef unsigned long long u64;
typedef __attribute__((ext_vector_type(4))) float f32x4;
typedef __attribute__((ext_vector_type(8))) short bf16x8;

constexpr int kT = 8192;   // sequence length
constexpr int kD = 512;    // word emb dim
constexpr int kH = 2048;   // hidden
constexpr int kH3 = 6144;  // 3*H
constexpr int kS = 512;    // segments
constexpr int kSeg = 16;   // tokens per segment
constexpr int kNWG2 = 256; // persistent WGs for upper GRU
constexpr int kREP = 8;    // h-broadcast replicas

__device__ __forceinline__ float bf2f(u16 u) {
  union { float f; u32 u; } v; v.u = ((u32)u) << 16; return v.f;
}
__device__ __forceinline__ u16 f2bf(float f) {
  union { float f; u32 u; } v; v.f = f;
  u32 lsb = (v.u >> 16) & 1u;
  v.u += 0x7fffu + lsb;          // round-to-nearest-even
  return (u16)(v.u >> 16);
}
// cheap packed-bf16 unpack: lo/hi half of a u32 as f32 (2 ops each)
__device__ __forceinline__ float bflo(u32 x) {
  union { float f; u32 u; } v; v.u = x << 16; return v.f;
}
__device__ __forceinline__ float bfhi(u32 x) {
  union { float f; u32 u; } v; v.u = x & 0xffff0000u; return v.f;
}
__device__ __forceinline__ float sigm(float x) { return 1.f / (1.f + expf(-x)); }

// async global->LDS, 16B per lane; LDS dest = wave-uniform base + lane*16
__device__ __forceinline__ void g2l16(const u16* g, u16* l) {
  __builtin_amdgcn_global_load_lds(
      (const __attribute__((address_space(1))) u32*)g,
      (__attribute__((address_space(3))) u32*)l, 16, 0, 0);
}

__device__ __forceinline__ u64 aload64(const u64* p) {
  return __hip_atomic_load(p, __ATOMIC_RELAXED, __HIP_MEMORY_SCOPE_AGENT);
}
__device__ __forceinline__ void astore64(u64* p, u64 v) {
  __hip_atomic_store(p, v, __ATOMIC_RELAXED, __HIP_MEMORY_SCOPE_AGENT);
}

// ---------------- f32 -> bf16 convert ----------------
__global__ void cvt_bf16(const float* __restrict__ in, u16* __restrict__ out, int n4) {
  int i = blockIdx.x * blockDim.x + threadIdx.x;
  if (i >= n4) return;
  const float4 v = *(const float4*)(in + (size_t)i * 4);
  uint2 o;
  o.x = (u32)f2bf(v.x) | ((u32)f2bf(v.y) << 16);
  o.y = (u32)f2bf(v.z) | ((u32)f2bf(v.w) << 16);
  *(uint2*)(out + (size_t)i * 4) = o;
}

// ---------------- bf16 GEMM  C = A(MxK,lda) * B(NxK,ldb)^T ----------------
// 4-deep software-pipelined staging (counted vmcnt + raw s_barrier; never
// drain-0 mid-loop). EPI 1: Obf = bf16(acc)   EPI 2: Obf = bf16(tanh(acc+bias))
template<int EPI>
__global__ __launch_bounds__(256)
void gemm_bt(const u16* __restrict__ A, int lda,
             const u16* __restrict__ B, int ldb,
             u16* __restrict__ Obf, const float* __restrict__ bias,
             int M, int N, int K)
{
  __shared__ u16 ls[4 * 16384];   // 4 bufs x (A 128x64 + B 128x64) = 128 KiB
  const int tid = threadIdx.x;
  const int w = tid >> 6, lane = tid & 63;
  const int wr = w >> 1, wc = w & 1;
  const int arow0 = blockIdx.y * 128;
  const int brow0 = blockIdx.x * 128;
  const int srow = w * 32 + (lane >> 3);
  const int scol = (lane & 7) * 8;
  const u16* gA = A + (size_t)(arow0 + srow) * lda + scol;
  const u16* gB = B + (size_t)(brow0 + srow) * ldb + scol;
  const int sb = w * 32 * 64;     // wave's staging base (rows w*32..)

  f32x4 acc[4][4];
#pragma unroll
  for (int m = 0; m < 4; ++m)
#pragma unroll
    for (int n = 0; n < 4; ++n) acc[m][n] = (f32x4)0.f;

  const int fr = lane & 15;
  const int kq = lane >> 4;
  const int nk = K >> 6;

  auto stage = [&](int buf, int kt) {
    u16* la = &ls[buf * 16384 + sb];
    u16* lb = &ls[buf * 16384 + 8192 + sb];
#pragma unroll
    for (int i = 0; i < 4; ++i) g2l16(gA + (size_t)i * 8 * lda + kt, la + i * 8 * 64);
#pragma unroll
    for (int i = 0; i < 4; ++i) g2l16(gB + (size_t)i * 8 * ldb + kt, lb + i * 8 * 64);
  };

  stage(0, 0);
  if (nk > 1) stage(1, 64);
  if (nk > 2) stage(2, 128);

  for (int i = 0; i < nk; ++i) {
    if (i + 2 < nk) asm volatile("s_waitcnt vmcnt(16)" ::: "memory");
    else            asm volatile("s_waitcnt vmcnt(0)" ::: "memory");
    __builtin_amdgcn_s_barrier();
    __builtin_amdgcn_sched_barrier(0);
    if (i + 3 < nk) stage((i + 3) & 3, (i + 3) * 64);
    const u16* lsA = &ls[(i & 3) * 16384];
    const u16* lsB = lsA + 8192;
#pragma unroll
    for (int kk = 0; kk < 2; ++kk) {
      bf16x8 af[4], bq[4];
#pragma unroll
      for (int m = 0; m < 4; ++m)
        af[m] = *(const bf16x8*)&lsA[(wr * 64 + m * 16 + fr) * 64 + kk * 32 + kq * 8];
#pragma unroll
      for (int n = 0; n < 4; ++n)
        bq[n] = *(const bf16x8*)&lsB[(wc * 64 + n * 16 + fr) * 64 + kk * 32 + kq * 8];
#pragma unroll
      for (int m = 0; m < 4; ++m)
#pragma unroll
        for (int n = 0; n < 4; ++n)
          acc[m][n] = __builtin_amdgcn_mfma_f32_16x16x32_bf16(af[m], bq[n], acc[m][n], 0, 0, 0);
    }
  }

#pragma unroll
  for (int m = 0; m < 4; ++m) {
#pragma unroll
    for (int n = 0; n < 4; ++n) {
      const int row0 = arow0 + wr * 64 + m * 16 + kq * 4;
      const int col = brow0 + wc * 64 + n * 16 + fr;
      if (EPI == 1) {
#pragma unroll
        for (int i = 0; i < 4; ++i)
          Obf[(size_t)(row0 + i) * N + col] = f2bf(acc[m][n][i]);
      } else {
        const float bv = bias[col];
#pragma unroll
        for (int i = 0; i < 4; ++i)
          Obf[(size_t)(row0 + i) * N + col] = f2bf(tanhf(acc[m][n][i] + bv));
      }
    }
  }
}

// ---------------- lower-GRU gates, paired-u32 bf16 I/O ----------------
__global__ __launch_bounds__(256) void gru1_gates(
    const u16* __restrict__ gi, const u16* __restrict__ gh,
    const float* __restrict__ bi, const float* __restrict__ bh,
    u16* __restrict__ h_bf, u16* __restrict__ outs_bf, int t)
{
  const int idx = blockIdx.x * 256 + threadIdx.x;  // 512*1024 pairs
  const int seg = idx >> 10, jp = idx & 1023;      // j = 2*jp
  const u32* gi32 = (const u32*)gi;
  const u32* gh32 = (const u32*)gh;
  const int base = seg * 3072;
  const u32 gir = gi32[base + jp],        ghr = gh32[base + jp];
  const u32 giz = gi32[base + 1024 + jp], ghz = gh32[base + 1024 + jp];
  const u32 gin = gi32[base + 2048 + jp], ghn = gh32[base + 2048 + jp];
  const float2 bir = *(const float2*)&bi[2 * jp];
  const float2 biz = *(const float2*)&bi[kH + 2 * jp];
  const float2 bin = *(const float2*)&bi[2 * kH + 2 * jp];
  const float2 bhr = *(const float2*)&bh[2 * jp];
  const float2 bhz = *(const float2*)&bh[kH + 2 * jp];
  const float2 bhn = *(const float2*)&bh[2 * kH + 2 * jp];
  const u32 hp = ((const u32*)h_bf)[seg * 1024 + jp];
  float hn[2];
#pragma unroll
  for (int e = 0; e < 2; ++e) {
    const float gr = e ? bfhi(gir) : bflo(gir), hr = e ? bfhi(ghr) : bflo(ghr);
    const float gz = e ? bfhi(giz) : bflo(giz), hz = e ? bfhi(ghz) : bflo(ghz);
    const float gn = e ? bfhi(gin) : bflo(gin), hh = e ? bfhi(ghn) : bflo(ghn);
    const float r = sigm(gr + (e ? bir.y : bir.x) + hr + (e ? bhr.y : bhr.x));
    const float z = sigm(gz + (e ? biz.y : biz.x) + hz + (e ? bhz.y : bhz.x));
    const float n = tanhf(gn + (e ? bin.y : bin.x) + r * (hh + (e ? bhn.y : bhn.x)));
    const float hprev = e ? bfhi(hp) : bflo(hp);
    hn[e] = (1.f - z) * n + z * hprev;
  }
  const u32 packed = (u32)f2bf(hn[0]) | ((u32)f2bf(hn[1]) << 16);
  ((u32*)h_bf)[seg * 1024 + jp] = packed;
  ((u32*)outs_bf)[(size_t)(seg * kSeg + t) * 1024 + jp] = packed;
}

// ---------------- degenerate softmax weight + per-segment column max ----------------
__global__ __launch_bounds__(256) void seg_weight_max(
    const u16* __restrict__ embh, const float* __restrict__ wa,
    u16* __restrict__ seg_bf)
{
  __shared__ float wrow[16];
  const int s = blockIdx.x, tid = threadIdx.x;
  const int w = tid >> 6, lane = tid & 63;
#pragma unroll
  for (int rr = 0; rr < 4; ++rr) {
    const int r = w * 4 + rr;
    const u16* row = embh + ((size_t)s * kSeg + r) * kH;
    float p = 0.f;
#pragma unroll
    for (int k = 0; k < 32; ++k) {
      const int c = lane + 64 * k;
      p += bf2f(row[c]) * wa[c];
    }
#pragma unroll
    for (int off = 32; off; off >>= 1) p += __shfl_down(p, off, 64);
    if (lane == 0) { const float e = expf(p); wrow[r] = e / (e + 1e-4f); }
  }
  __syncthreads();
#pragma unroll
  for (int i = 0; i < 8; ++i) {
    const int c = tid + 256 * i;
    float m = -1e30f;
#pragma unroll
    for (int r = 0; r < 16; ++r)
      m = fmaxf(m, wrow[r] * bf2f(embh[((size_t)s * kSeg + r) * kH + c]));
    seg_bf[(size_t)s * kH + c] = f2bf(m);
  }
}

// ---------------- upper GRU: persistent, 512 steps, TAGGED DATAFLOW sync ----
// h broadcast words are u64 = (step_tag << 32) | (2 x bf16). Consumers poll
// their own words until tag >= t: the poll IS the sync AND the data load.
// No barrier. Double-buffered by step parity; tag monotonicity proves no
// clobber (writer of tag t+1 implies all WGs finished reading tag t-1 slot).
__global__ __launch_bounds__(512)
void gru2_persistent(const u16* __restrict__ Wh2bf, const u16* __restrict__ gi2b,
                     const float* __restrict__ bi2, const float* __restrict__ bh2,
                     u64* __restrict__ hrep,      // [2][kREP][1024] tagged u64
                     u16* __restrict__ outs2)     // 512*2048 bf16
{
  __shared__ u16 wl[24 * kH];                 // 96 KiB weights (24 rows)
  __shared__ u32 hlb[1024];                   // 4 KiB: h as packed bf16 pairs
  __shared__ float gil_all[512 * 24];         // 48 KiB gi2 slice
  __shared__ float rowsum[24];
  __shared__ alignas(16) u16 hnl[8];
  const int wg = blockIdx.x, tid = threadIdx.x;
  const int g0 = wg * 8;
  const int grp = wg & 7;
  // weights: 24 rows x 256 uint4
  uint4* wl4 = (uint4*)wl;
  for (int i = tid; i < 24 * 256; i += 512) {
    const int lr = i >> 8, q = i & 255;
    const int grow = (lr >> 3) * kH + g0 + (lr & 7);
    wl4[i] = ((const uint4*)Wh2bf)[(size_t)grow * 256 + q];
  }
  for (int i = tid; i < 512 * 24; i += 512) {
    const int t = i / 24, idx = i - t * 24;
    gil_all[i] = bf2f(gi2b[(size_t)t * kH3 + (idx >> 3) * kH + g0 + (idx & 7)]);
  }
  float bir = 0, biz = 0, bin = 0, bhr = 0, bhz = 0, bhn = 0;
  if (tid < 8) {
    const int jj = g0 + tid;
    bir = bi2[jj]; biz = bi2[kH + jj]; bin = bi2[2 * kH + jj];
    bhr = bh2[jj]; bhz = bh2[kH + jj]; bhn = bh2[2 * kH + jj];
  }
  const int w = tid >> 6, lane = tid & 63;
  const uint4* hl4 = (const uint4*)hlb;

  for (int t = 0; t < 512; ++t) {
    // ---- poll-in: 2 tagged u64 per thread from own replica ----
    const u64* hs = hrep + ((size_t)(t & 1) * kREP + grp) * 1024;
    u64 v0, v1;
    for (;;) {
      v0 = aload64(&hs[2 * tid]);
      if ((u32)(v0 >> 32) >= (u32)t) break;
      __builtin_amdgcn_s_sleep(1);
    }
    for (;;) {
      v1 = aload64(&hs[2 * tid + 1]);
      if ((u32)(v1 >> 32) >= (u32)t) break;
      __builtin_amdgcn_s_sleep(1);
    }
    hlb[2 * tid] = (u32)v0;
    hlb[2 * tid + 1] = (u32)v1;
    __syncthreads();
    // ---- matvec: 3 rows per wave, uint4 LDS reads, 2-op unpack ----
#pragma unroll
    for (int rr = 0; rr < 3; ++rr) {
      const int lr = w * 3 + rr;
      float p = 0.f;
#pragma unroll
      for (int k = 0; k < 4; ++k) {
        const int q = lane + 64 * k;
        const uint4 wv = wl4[lr * 256 + q];
        const uint4 hv = hl4[q];
        p += bflo(wv.x) * bflo(hv.x) + bfhi(wv.x) * bfhi(hv.x);
        p += bflo(wv.y) * bflo(hv.y) + bfhi(wv.y) * bfhi(hv.y);
        p += bflo(wv.z) * bflo(hv.z) + bfhi(wv.z) * bfhi(hv.z);
        p += bflo(wv.w) * bflo(hv.w) + bfhi(wv.w) * bfhi(hv.w);
      }
#pragma unroll
      for (int off = 32; off; off >>= 1) p += __shfl_down(p, off, 64);
      if (lane == 0) rowsum[lr] = p;
    }
    __syncthreads();
    // ---- gates ----
    if (tid < 8) {
      const float r = sigm(gil_all[t * 24 + tid] + bir + rowsum[tid] + bhr);
      const float z = sigm(gil_all[t * 24 + 8 + tid] + biz + rowsum[8 + tid] + bhz);
      const float n = tanhf(gil_all[t * 24 + 16 + tid] + bin +
                            r * (rowsum[16 + tid] + bhn));
      const u32 hw = hlb[(g0 + tid) >> 1];
      const float hprev = (tid & 1) ? bfhi(hw) : bflo(hw);
      hnl[tid] = f2bf((1.f - z) * n + z * hprev);
    }
    __syncthreads();
    // ---- tagged broadcast-out: 4 words x kREP replicas ----
    if (tid < 4 * kREP) {
      const int rep = tid >> 2, k = tid & 3;
      const u64 val = ((u64)(u32)(t + 1) << 32) | ((const u32*)hnl)[k];
      astore64(&hrep[((size_t)((t + 1) & 1) * kREP + rep) * 1024 + wg * 4 + k], val);
    }
    if (tid == 0)
      *(uint4*)&outs2[(size_t)t * kH + g0] = *(const uint4*)hnl;
  }
}

// ---------------- w2 then final column max ----------------
__global__ void calc_w2(const u16* __restrict__ e2, const float* __restrict__ wa2,
                        float* __restrict__ w2) {
  const int s = blockIdx.x, lane = threadIdx.x;  // 64 threads
  float p = 0.f;
#pragma unroll
  for (int k = 0; k < 32; ++k) {
    const int c = lane + 64 * k;
    p += bf2f(e2[(size_t)s * kH + c]) * wa2[c];
  }
#pragma unroll
  for (int off = 32; off; off >>= 1) p += __shfl_down(p, off, 64);
  if (lane == 0) { const float e = expf(p); w2[s] = e / (e + 1e-4f); }
}

__global__ void final_max(const u16* __restrict__ e2, const float* __restrict__ w2,
                          float* __restrict__ out) {
  const int j = blockIdx.x * blockDim.x + threadIdx.x;  // 2048
  float m = -1e30f;
  for (int s = 0; s < 512; ++s)
    m = fmaxf(m, w2[s] * bf2f(e2[(size_t)s * kH + j]));
  out[j] = m;
}

// ---------------- host ----------------
extern "C" void kernel_launch(void* const* d_in, const int* in_sizes, int n_in,
                              void* d_out, int out_size, void* d_ws, size_t ws_size,
                              hipStream_t stream)
{
  (void)in_sizes; (void)n_in; (void)out_size; (void)ws_size;
  const float* sent = (const float*)d_in[0];
  const float* Wi1f = (const float*)d_in[1];
  const float* Wh1f = (const float*)d_in[2];
  const float* bi1  = (const float*)d_in[3];
  const float* bh1  = (const float*)d_in[4];
  const float* Wi2f = (const float*)d_in[5];
  const float* Wh2f = (const float*)d_in[6];
  const float* bi2  = (const float*)d_in[7];
  const float* bh2  = (const float*)d_in[8];
  const float* Wlf  = (const float*)d_in[9];
  const float* bl   = (const float*)d_in[10];
  const float* wa   = (const float*)d_in[11];
  const float* Wl2f = (const float*)d_in[12];
  const float* bl2  = (const float*)d_in[13];
  const float* wa2  = (const float*)d_in[14];
  float* out = (float*)d_out;

  char* base = (char*)d_ws;
  size_t off = 0;
  auto alloc = [&](size_t b) { char* p = base + off; off += (b + 255) & ~(size_t)255; return p; };
  u16* sent_bf = (u16*)alloc((size_t)kT * kD * 2);   // dead after phase B -> embh alias
  u16* Wi1b    = (u16*)alloc((size_t)kH3 * kD * 2);
  u16* Wh1b    = (u16*)alloc((size_t)kH3 * kH * 2);
  u16* Wi2b    = (u16*)alloc((size_t)kH3 * kH * 2);
  u16* Wh2b    = (u16*)alloc((size_t)kH3 * kH * 2);
  u16* Wlb     = (u16*)alloc((size_t)kH * kH * 2);
  u16* Wl2b    = (u16*)alloc((size_t)kH * kH * 2);
  u16* gi_buf  = (u16*)alloc((size_t)kS * kH3 * 2);  // bf16 now
  u16* gh_buf  = (u16*)alloc((size_t)kS * kH3 * 2);
  u16* h1b     = (u16*)alloc((size_t)kS * kH * 2);
  u16* outs_bf = (u16*)alloc((size_t)kT * kH * 2);
  u16* seg_bf  = (u16*)alloc((size_t)kS * kH * 2);
  u64* hrep    = (u64*)alloc((size_t)2 * kREP * 1024 * 8);
  u16* outs2   = (u16*)alloc((size_t)kS * kH * 2);
  u16* e2b     = (u16*)alloc((size_t)kS * kH * 2);
  float* w2    = (float*)alloc(kS * 4);
  // aliases over dead regions
  u16* embh = sent_bf;   // 33.5 MB fits in sent_bf+Wi1b+Wh1b (39.8 MB)
  u16* gi2b = gi_buf;

  hipMemsetAsync(h1b, 0, (size_t)kS * kH * 2, stream);
  hipMemsetAsync(hrep, 0, (size_t)2 * kREP * 1024 * 8, stream);

  auto cvt = [&](const float* src, u16* dst, int n) {
    const int n4 = n / 4;
    cvt_bf16<<<dim3((n4 + 255) / 256), dim3(256), 0, stream>>>(src, dst, n4);
  };
  cvt(sent, sent_bf, kT * kD);
  cvt(Wi1f, Wi1b, kH3 * kD);
  cvt(Wh1f, Wh1b, kH3 * kH);
  cvt(Wi2f, Wi2b, kH3 * kH);
  cvt(Wh2f, Wh2b, kH3 * kH);
  cvt(Wlf, Wlb, kH * kH);
  cvt(Wl2f, Wl2b, kH * kH);

  // ---- phase B: lower GRU, 16 batched steps over 512 independent chains ----
  for (int t = 0; t < kSeg; ++t) {
    gemm_bt<1><<<dim3(kH3 / 128, kS / 128), dim3(256), 0, stream>>>(
        h1b, kH, Wh1b, kH, gh_buf, nullptr, kS, kH3, kH);
    gemm_bt<1><<<dim3(kH3 / 128, kS / 128), dim3(256), 0, stream>>>(
        sent_bf + t * kD, kSeg * kD, Wi1b, kD, gi_buf, nullptr, kS, kH3, kD);
    gru1_gates<<<dim3(kS * kH / 512), dim3(256), 0, stream>>>(
        gi_buf, gh_buf, bi1, bh1, h1b, outs_bf, t);
  }
  // ---- phase C: emb_h = tanh(outs @ Wl^T + bl) ----
  gemm_bt<2><<<dim3(kH / 128, kT / 128), dim3(256), 0, stream>>>(
      outs_bf, kH, Wlb, kH, embh, bl, kT, kH, kH);
  // ---- phase D: w, weighted, segment max ----
  seg_weight_max<<<dim3(kS), dim3(256), 0, stream>>>(embh, wa, seg_bf);
  // ---- phase E: gi2 = seg @ Wi2^T (bf16) ----
  gemm_bt<1><<<dim3(kH3 / 128, kS / 128), dim3(256), 0, stream>>>(
      seg_bf, kH, Wi2b, kH, gi2b, nullptr, kS, kH3, kH);
  // ---- phase F: upper GRU, 512 sequential steps, tagged-dataflow ----
  gru2_persistent<<<dim3(kNWG2), dim3(512), 0, stream>>>(
      Wh2b, gi2b, bi2, bh2, hrep, outs2);
  // ---- phase G: e2 = tanh(outs2 @ Wl2^T + bl2), w2, final max ----
  gemm_bt<2><<<dim3(kH / 128, kS / 128), dim3(256), 0, stream>>>(
      outs2, kH, Wl2b, kH, e2b, bl2, kS, kH, kH);
  calc_w2<<<dim3(kS), dim3(64), 0, stream>>>(e2b, wa2, w2);
  final_max<<<dim3(kH / 256), dim3(256), 0, stream>>>(e2b, w2, out);
}